// Round 8
// baseline (144.232 us; speedup 1.0000x reference)
//
#include <hip/hip_runtime.h>

typedef __bf16 bfx8 __attribute__((ext_vector_type(8)));
typedef float f32x4 __attribute__((ext_vector_type(4)));
typedef unsigned short u16x8 __attribute__((ext_vector_type(8)));

#define MFMA16(a, b, c) __builtin_amdgcn_mfma_f32_16x16x32_bf16((a), (b), (c), 0, 0, 0)

#define GLOAD16(gp, lp)                                                        \
  __builtin_amdgcn_global_load_lds(                                            \
      (const __attribute__((address_space(1))) unsigned int*)(gp),             \
      (__attribute__((address_space(3))) unsigned int*)(lp), 16, 0, 0)

// Geometry: x (8, 256, 16384) fp32; mem (200, 256) fp32; out (8, 256, 16384) fp32.
// Slots padded 200 -> 256 with zero rows.

// ---------------- prep: mem -> bf16 hi/lo + permuted-transposed hi ----------------
// MTp[c][kidx] = hi(mem[sigma(kidx)][c]), sigma(32ks+8h+4t+r) -> slot 32ks+16t+4h+r,
// so the PV B-operand is a pure in-register repack of the score accumulators.
__global__ __launch_bounds__(256) void prep_mem(const float* __restrict__ mem,
                                                unsigned short* __restrict__ Mh,
                                                unsigned short* __restrict__ Ml,
                                                unsigned short* __restrict__ MTp) {
  const int s = blockIdx.x;   // slot (padded)
  const int c = threadIdx.x;  // channel
  const float v = (s < 200) ? mem[s * 256 + c] : 0.0f;
  const __bf16 hi = (__bf16)v;
  const __bf16 lo = (__bf16)(v - (float)hi);
  const unsigned short hib = __builtin_bit_cast(unsigned short, hi);
  const unsigned short lob = __builtin_bit_cast(unsigned short, lo);
  Mh[s * 256 + c] = hib;
  Ml[s * 256 + c] = lob;
  const int ks = s >> 5, w = s & 31;
  const int t = w >> 4, hh = (w >> 2) & 3, rr = w & 3;
  MTp[c * 256 + (ks * 32 + hh * 8 + t * 4 + rr)] = hib;
}

// ---------------- fused kernel ----------------
// Block = 8 waves x 16 tokens = 128 tokens, 512 threads. Grid = 1024.
// LDS 64KB -> TWO blocks/CU co-resident (16 waves/CU, 4/SIMD): block A's
// epilogue writes overlap block B's score reads; barrier drains overlap.
// LDS: Mh ping-pong (2x16KB) at 0/16K; MTp ping-pong (2x16KB) at 32K/48K.
// Ml fragments read direct from L2/L1 (8 lockstep waves -> L1 reuse).
// All __syncthreads full drains; stage-2-ahead AFTER each barrier (race-free).
__global__ __launch_bounds__(512, 4) void fused_mem_attn(
    const float* __restrict__ x, const unsigned short* __restrict__ Mh,
    const unsigned short* __restrict__ Ml, const unsigned short* __restrict__ MTp,
    float* __restrict__ out) {
  __shared__ alignas(128) char lds[65536];

  const int tid = threadIdx.x;   // 0..511
  const int wave = tid >> 6;     // 0..7
  const int lane = tid & 63;
  const int t16 = lane & 15;
  const int h = lane >> 4;

  // Staging: thread owns physical 16B-blocks P = it*512+tid of a 16KB slice;
  // fetch logical L = P ^ ((P>>3)&7) (involution) -> LDS content XOR-swizzled
  // while the global_load_lds destination stays linear.
  int srcOff[2];
#pragma unroll
  for (int it = 0; it < 2; ++it) {
    const int P = it * 512 + tid;
    const int L = P ^ ((P >> 3) & 7);
    srcOff[it] = (L >> 2) * 512 + (L & 3) * 16;  // byte in [256 rows][64B]
  }

  // Reader-side swizzled block byte offset within a 1KB (16-row) tile.
  const int q16 = ((((t16 << 2) + h) ^ (t16 >> 1)) << 4);

  const long gtok0 = (long)blockIdx.x * 128 + (long)(wave * 16);
  const int b = (int)(gtok0 >> 14);
  const int n0 = (int)(gtok0 & 16383);
  const float* xb = x + ((long)b << 22) + n0 + t16;

  const char* MhB = (const char*)Mh;
  const char* MlB = (const char*)Ml;
  const char* MTB = (const char*)MTp;

#define STAGE_S(ks)                                                            \
  _Pragma("unroll") for (int it = 0; it < 2; ++it)                             \
      GLOAD16(MhB + srcOff[it] + (ks) * 64,                                    \
              lds + ((ks) & 1) * 16384 + (it * 512 + tid) * 16);

#define STAGE_PV(k)                                                            \
  _Pragma("unroll") for (int it = 0; it < 2; ++it)                             \
      GLOAD16(MTB + srcOff[it] + (k) * 64,                                     \
              lds + 32768 + ((k) & 1) * 16384 + (it * 512 + tid) * 16);

#define XLOAD(ks)                                                              \
  _Pragma("unroll") for (int j = 0; j < 8; ++j) {                              \
    xr[(ks) & 1][j] = xb[(long)((ks) * 32 + h * 8 + j) << 14];                 \
  }

  float xr[2][8];
  f32x4 acc[14] = {};  // acc[13] stays exactly 0 (padding slots 208..223)

#define COMPUTE(ks)                                                            \
  {                                                                            \
    bfx8 xh, xl;                                                               \
    _Pragma("unroll") for (int j = 0; j < 8; ++j) {                            \
      const float f = xr[(ks) & 1][j];                                         \
      const __bf16 hi_ = (__bf16)f;                                            \
      xh[j] = hi_;                                                             \
      xl[j] = (__bf16)(f - (float)hi_);                                        \
    }                                                                          \
    const char* sb = lds + ((ks) & 1) * 16384;                                 \
    __builtin_amdgcn_s_setprio(1);                                             \
    _Pragma("unroll") for (int tt = 0; tt < 13; ++tt) {                        \
      const bfx8 ah = *(const bfx8*)(sb + tt * 1024 + q16);                    \
      const u16x8 mlu =                                                        \
          *(const u16x8*)(MlB + (tt * 16 + t16) * 512 + (ks) * 64 + h * 16);   \
      const bfx8 al = __builtin_bit_cast(bfx8, mlu);                           \
      acc[tt] = MFMA16(ah, xh, acc[tt]);                                       \
      acc[tt] = MFMA16(al, xh, acc[tt]);                                       \
      acc[tt] = MFMA16(ah, xl, acc[tt]);                                       \
    }                                                                          \
    __builtin_amdgcn_s_setprio(0);                                             \
  }

  // ---- prologue: stage Mh slices 0,1; prefetch x slice 0 ----
  STAGE_S(0);
  STAGE_S(1);
  XLOAD(0);
  __syncthreads();  // publishes slices 0,1 (full drain)

  // ---- score phase: per-iter full-drain barrier; stage 2-ahead AFTER it ----
#pragma unroll
  for (int ks = 0; ks < 8; ++ks) {
    if (ks < 7) XLOAD(ks + 1);
    COMPUTE(ks)
    __syncthreads();  // all waves done reading sbuf(ks&1); drains x(ks+1)
    if (ks < 6) {
      STAGE_S(ks + 2);     // into sbuf(ks&1): readers provably done
    } else if (ks == 6) {
      STAGE_PV(0);         // drained at ks=7's barrier
    } else {
      STAGE_PV(1);         // drained at the post-softmax barrier
    }
  }

  // ---- softmax over slots (token column = lane&15; slot row = 4h+r) ----
  float m = -3.0e38f;
#pragma unroll
  for (int tt = 0; tt < 12; ++tt)
#pragma unroll
    for (int r = 0; r < 4; ++r) m = fmaxf(m, acc[tt][r]);
#pragma unroll
  for (int r = 0; r < 4; ++r)
    if (192 + h * 4 + r < 200) m = fmaxf(m, acc[12][r]);
  m = fmaxf(m, __shfl_xor(m, 16, 64));
  m = fmaxf(m, __shfl_xor(m, 32, 64));
  float s = 0.f;
#pragma unroll
  for (int tt = 0; tt < 12; ++tt)
#pragma unroll
    for (int r = 0; r < 4; ++r) {
      const float p = __expf(acc[tt][r] - m);
      acc[tt][r] = p;
      s += p;
    }
#pragma unroll
  for (int r = 0; r < 4; ++r) {
    const bool ok = (192 + h * 4 + r) < 200;
    const float p = ok ? __expf(acc[12][r] - m) : 0.f;
    acc[12][r] = p;
    s += p;
  }
  s += __shfl_xor(s, 16, 64);
  s += __shfl_xor(s, 32, 64);
  const float inv = 1.f / s;

  // ---- repack P into PV B-fragments in registers (sigma baked into MTp) ----
  bfx8 pb[7];
#pragma unroll
  for (int k = 0; k < 7; ++k)
#pragma unroll
    for (int j = 0; j < 4; ++j) {
      pb[k][j] = (__bf16)acc[2 * k][j];
      pb[k][j + 4] = (__bf16)acc[2 * k + 1][j];
    }

  __syncthreads();  // publishes PV1 (PV0 already published at ks=7's barrier)

  // ---- PV: out^T[c][token] = sum_kidx MTp[c][kidx]*P[sigma(kidx)][token] ----
  f32x4 acc2[16] = {};
#pragma unroll
  for (int k = 0; k < 7; ++k) {
    const char* pv = lds + 32768 + (k & 1) * 16384;
    __builtin_amdgcn_s_setprio(1);
#pragma unroll
    for (int ct = 0; ct < 16; ++ct) {
      const bfx8 at = *(const bfx8*)(pv + ct * 1024 + q16);
      acc2[ct] = MFMA16(at, pb[k], acc2[ct]);
    }
    __builtin_amdgcn_s_setprio(0);
    if (k < 6) {
      __syncthreads();              // readers of pvbuf(k&1) done; drains stage(k+1)
      if (k < 5) STAGE_PV(k + 2);   // into pvbuf(k&1); visible after next barrier
    }
  }

  // ---- epilogue: normalize, store out[b][c][n] ----
  float* ob = out + ((long)b << 22) + n0 + t16;
#pragma unroll
  for (int ct = 0; ct < 16; ++ct)
#pragma unroll
    for (int r = 0; r < 4; ++r) {
      ob[(long)(ct * 16 + h * 4 + r) << 14] = acc2[ct][r] * inv;
    }
#undef STAGE_S
#undef STAGE_PV
#undef XLOAD
#undef COMPUTE
}

extern "C" void kernel_launch(void* const* d_in, const int* in_sizes, int n_in,
                              void* d_out, int out_size, void* d_ws, size_t ws_size,
                              hipStream_t stream) {
  const float* x = (const float*)d_in[0];
  const float* mem = (const float*)d_in[1];
  float* out = (float*)d_out;

  unsigned short* Mh = (unsigned short*)d_ws;  // [256][256] bf16 hi
  unsigned short* Ml = Mh + 256 * 256;         // [256][256] bf16 lo
  unsigned short* MTp = Ml + 256 * 256;        // [256][256] bf16 hi, [c][kidx] permuted

  prep_mem<<<dim3(256), dim3(256), 0, stream>>>(mem, Mh, Ml, MTp);
  fused_mem_attn<<<dim3(1024), dim3(512), 0, stream>>>(x, Mh, Ml, MTp, out);
}

// Round 9
// 81.217 us; speedup vs baseline: 1.7759x; 1.7759x over previous
//
#include <hip/hip_runtime.h>

typedef __bf16 bfx8 __attribute__((ext_vector_type(8)));
typedef float f32x4 __attribute__((ext_vector_type(4)));

#define MFMA16(a, b, c) __builtin_amdgcn_mfma_f32_16x16x32_bf16((a), (b), (c), 0, 0, 0)

#define GLOAD16(gp, lp)                                                        \
  __builtin_amdgcn_global_load_lds(                                            \
      (const __attribute__((address_space(1))) unsigned int*)(gp),             \
      (__attribute__((address_space(3))) unsigned int*)(lp), 16, 0, 0)

// Geometry: x (8, 256, 16384) fp32; mem (200, 256) fp32; out (8, 256, 16384) fp32.
// Slots padded 200 -> 256 with zero rows.

// ---------------- prep: mem -> bf16 hi/lo + permuted-transposed hi ----------------
// MTp[c][kidx] = hi(mem[sigma(kidx)][c]), sigma(32ks+8h+4t+r) -> slot 32ks+16t+4h+r,
// so the PV B-operand is a pure in-register repack of the score accumulators.
__global__ __launch_bounds__(256) void prep_mem(const float* __restrict__ mem,
                                                unsigned short* __restrict__ Mh,
                                                unsigned short* __restrict__ Ml,
                                                unsigned short* __restrict__ MTp) {
  const int s = blockIdx.x;   // slot (padded)
  const int c = threadIdx.x;  // channel
  const float v = (s < 200) ? mem[s * 256 + c] : 0.0f;
  const __bf16 hi = (__bf16)v;
  const __bf16 lo = (__bf16)(v - (float)hi);
  const unsigned short hib = __builtin_bit_cast(unsigned short, hi);
  const unsigned short lob = __builtin_bit_cast(unsigned short, lo);
  Mh[s * 256 + c] = hib;
  Ml[s * 256 + c] = lob;
  const int ks = s >> 5, w = s & 31;
  const int t = w >> 4, hh = (w >> 2) & 3, rr = w & 3;
  MTp[c * 256 + (ks * 32 + hh * 8 + t * 4 + rr)] = hib;
}

// ---------------- fused kernel ----------------
// Block = 16 waves x 16 tokens = 256 tokens, 1024 threads. Grid = 512 (2 rounds).
// LDS 128KB: Mr (64KB) = mem hi/lo slice ping-pong, later MTp slices 0..3;
//            Xr (64KB) = x slice ping-pong (32ch x 256tok fp32, 1KB rows),
//                        later MTp slices 4..6, then epilogue transpose chunks.
// All HBM traffic is 1KB-contiguous: x staged per channel-row via gload_lds;
// out written per channel-row after an LDS transpose of acc2.
__global__ __launch_bounds__(1024, 4) void fused_mem_attn(
    const float* __restrict__ x, const unsigned short* __restrict__ Mh,
    const unsigned short* __restrict__ Ml, const unsigned short* __restrict__ MTp,
    float* __restrict__ out) {
  __shared__ alignas(128) char lds[131072];
  char* Mr = lds;            // 64KB
  char* Xr = lds + 65536;    // 64KB

  const int tid = threadIdx.x;   // 0..1023
  const int wave = tid >> 6;     // 0..15
  const int lane = tid & 63;
  const int t16 = lane & 15;
  const int h = lane >> 4;

  // mem staging swizzle (R7-proven pair): thread owns physical 16B-block tid of
  // each 16KB slice; fetches logical Lb = tid ^ ((tid>>3)&7) (involution).
  const int Lb = tid ^ ((tid >> 3) & 7);
  const int srcOff = (Lb >> 2) * 512 + (Lb & 3) * 16;  // byte in [256 rows][64B]
  // Reader-side swizzled 16B-block offset within a 1KB (16-row) tile.
  const int q16 = ((((t16 << 2) + h) ^ (t16 >> 1)) << 4);

  const long btok = (long)blockIdx.x * 256;      // block's first token
  const int b = (int)(btok >> 14);
  const int bn0 = (int)(btok & 16383);           // 256-aligned spatial base

  const char* MhB = (const char*)Mh;
  const char* MlB = (const char*)Ml;
  const char* MTB = (const char*)MTp;
  const char* xB = (const char*)(x + ((long)b << 22) + bn0);
  float* outB = out + ((long)b << 22) + bn0;

  // mem hi/lo slice ks -> Mr[(ks&1)] (hi at +0, lo at +16K)
#define STAGE_S(ks)                                                            \
  {                                                                            \
    GLOAD16(MhB + srcOff + (ks) * 64, Mr + ((ks) & 1) * 32768 + tid * 16);     \
    GLOAD16(MlB + srcOff + (ks) * 64,                                          \
            Mr + ((ks) & 1) * 32768 + 16384 + tid * 16);                       \
  }

  // x slice ks: 32 channel rows, each 1KB contiguous in global AND LDS.
  // Wave w stages rows w and w+16 (one gload_lds instruction per row).
#define STAGE_X(ks)                                                            \
  {                                                                            \
    GLOAD16(xB + ((long)((ks) * 32 + wave) << 16) + lane * 16,                 \
            Xr + ((ks) & 1) * 32768 + wave * 1024 + lane * 16);                \
    GLOAD16(xB + ((long)((ks) * 32 + wave + 16) << 16) + lane * 16,            \
            Xr + ((ks) & 1) * 32768 + (wave + 16) * 1024 + lane * 16);         \
  }

  // MTp slice k: 0..3 -> Mr, 4..6 -> Xr (k is a literal; ternary folds)
#define STAGE_PV(k)                                                            \
  GLOAD16(MTB + srcOff + (k) * 64,                                             \
          ((k) < 4 ? Mr + (k) * 16384 : Xr + ((k) - 4) * 16384) + tid * 16);

  f32x4 acc[14] = {};  // acc[13] stays exactly 0 (padding slots 208..223)

#define COMPUTE(ks)                                                            \
  {                                                                            \
    const char* xs = Xr + ((ks) & 1) * 32768;                                  \
    float xf[8];                                                               \
    _Pragma("unroll") for (int j = 0; j < 8; ++j) xf[j] =                      \
        *(const float*)(xs + (h * 8 + j) * 1024 + ((wave * 16 + t16) << 2));   \
    bfx8 xh, xl;                                                               \
    _Pragma("unroll") for (int j = 0; j < 8; ++j) {                            \
      const __bf16 hi_ = (__bf16)xf[j];                                        \
      xh[j] = hi_;                                                             \
      xl[j] = (__bf16)(xf[j] - (float)hi_);                                    \
    }                                                                          \
    const char* sb = Mr + ((ks) & 1) * 32768;                                  \
    __builtin_amdgcn_s_setprio(1);                                             \
    _Pragma("unroll") for (int tt = 0; tt < 13; ++tt) {                        \
      const bfx8 ah = *(const bfx8*)(sb + tt * 1024 + q16);                    \
      const bfx8 al = *(const bfx8*)(sb + 16384 + tt * 1024 + q16);            \
      acc[tt] = MFMA16(ah, xh, acc[tt]);                                       \
      acc[tt] = MFMA16(al, xh, acc[tt]);                                       \
      acc[tt] = MFMA16(ah, xl, acc[tt]);                                       \
    }                                                                          \
    __builtin_amdgcn_s_setprio(0);                                             \
  }

  // ---- prologue: slices 0,1 of mem and x ----
  STAGE_S(0); STAGE_S(1); STAGE_X(0); STAGE_X(1);
  __syncthreads();

  // ---- score loop: compute(ks) -> sync -> stage(ks+2) into freed buffer ----
  COMPUTE(0) __syncthreads(); STAGE_S(2); STAGE_X(2);
  COMPUTE(1) __syncthreads(); STAGE_S(3); STAGE_X(3);
  COMPUTE(2) __syncthreads(); STAGE_S(4); STAGE_X(4);
  COMPUTE(3) __syncthreads(); STAGE_S(5); STAGE_X(5);
  COMPUTE(4) __syncthreads(); STAGE_S(6); STAGE_X(6);
  COMPUTE(5) __syncthreads(); STAGE_S(7); STAGE_X(7);
  COMPUTE(6) __syncthreads();
  STAGE_PV(0); STAGE_PV(1); STAGE_PV(4); STAGE_PV(5);  // into freed buf0 halves
  COMPUTE(7) __syncthreads();
  STAGE_PV(2); STAGE_PV(3); STAGE_PV(6);               // into freed buf1 halves

  // ---- softmax over slots (token column = lane&15; slot row = 4h+r) ----
  // (MTp staging latency hides under this register-only phase.)
  float m = -3.0e38f;
#pragma unroll
  for (int tt = 0; tt < 12; ++tt)
#pragma unroll
    for (int r = 0; r < 4; ++r) m = fmaxf(m, acc[tt][r]);
#pragma unroll
  for (int r = 0; r < 4; ++r)
    if (192 + h * 4 + r < 200) m = fmaxf(m, acc[12][r]);
  m = fmaxf(m, __shfl_xor(m, 16, 64));
  m = fmaxf(m, __shfl_xor(m, 32, 64));
  float s = 0.f;
#pragma unroll
  for (int tt = 0; tt < 12; ++tt)
#pragma unroll
    for (int r = 0; r < 4; ++r) {
      const float p = __expf(acc[tt][r] - m);
      acc[tt][r] = p;
      s += p;
    }
#pragma unroll
  for (int r = 0; r < 4; ++r) {
    const bool ok = (192 + h * 4 + r) < 200;
    const float p = ok ? __expf(acc[12][r] - m) : 0.f;
    acc[12][r] = p;
    s += p;
  }
  s += __shfl_xor(s, 16, 64);
  s += __shfl_xor(s, 32, 64);
  const float inv = 1.f / s;

  // ---- repack P into PV B-fragments in registers (sigma baked into MTp) ----
  bfx8 pb[7];
#pragma unroll
  for (int k = 0; k < 7; ++k)
#pragma unroll
    for (int j = 0; j < 4; ++j) {
      pb[k][j] = (__bf16)acc[2 * k][j];
      pb[k][j + 4] = (__bf16)acc[2 * k + 1][j];
    }

  __syncthreads();  // all 7 MTp slices resident

  // ---- PV: barrier-free. out^T[c][tok] = sum_kidx MTp[c][kidx]*P[..] ----
  f32x4 acc2[16] = {};
#pragma unroll
  for (int k = 0; k < 7; ++k) {
    const char* pv = (k < 4) ? (Mr + k * 16384) : (Xr + (k - 4) * 16384);
    __builtin_amdgcn_s_setprio(1);
#pragma unroll
    for (int ct = 0; ct < 16; ++ct) {
      const bfx8 at = *(const bfx8*)(pv + ct * 1024 + q16);
      acc2[ct] = MFMA16(at, pb[k], acc2[ct]);
    }
    __builtin_amdgcn_s_setprio(0);
  }

  __syncthreads();  // PV LDS reads done; Xr free for epilogue chunks

  // ---- epilogue: LDS-transpose to 1KB-contiguous channel-row stores ----
  // Chunk cc = channels [32cc, 32cc+32): ping-pong 32KB buffers in Xr.
#pragma unroll
  for (int cc = 0; cc < 8; ++cc) {
    char* E = Xr + (cc & 1) * 32768;
#pragma unroll
    for (int ctp = 0; ctp < 2; ++ctp)
#pragma unroll
      for (int r = 0; r < 4; ++r)
        *(float*)(E + ((ctp * 16 + h * 4 + r) << 10) +
                  ((wave * 16 + t16) << 2)) = acc2[2 * cc + ctp][r] * inv;
    __syncthreads();  // chunk visible; prior reads of this buffer proven done
#pragma unroll
    for (int ss = 0; ss < 2; ++ss) {
      const int u = tid + (ss << 10);
      const int row = u >> 6;      // channel within chunk
      const int col = u & 63;      // 16B token group
      const f32x4 v = *(const f32x4*)(E + row * 1024 + col * 16);
      *(f32x4*)(outB + ((long)(cc * 32 + row) << 14) + col * 4) = v;
    }
  }
#undef STAGE_S
#undef STAGE_X
#undef STAGE_PV
#undef COMPUTE
}

extern "C" void kernel_launch(void* const* d_in, const int* in_sizes, int n_in,
                              void* d_out, int out_size, void* d_ws, size_t ws_size,
                              hipStream_t stream) {
  const float* x = (const float*)d_in[0];
  const float* mem = (const float*)d_in[1];
  float* out = (float*)d_out;

  unsigned short* Mh = (unsigned short*)d_ws;  // [256][256] bf16 hi
  unsigned short* Ml = Mh + 256 * 256;         // [256][256] bf16 lo
  unsigned short* MTp = Ml + 256 * 256;        // [256][256] bf16 hi, [c][kidx] permuted

  prep_mem<<<dim3(256), dim3(256), 0, stream>>>(mem, Mh, Ml, MTp);
  fused_mem_attn<<<dim3(512), dim3(1024), 0, stream>>>(x, Mh, Ml, MTp, out);
}